// Round 4
// baseline (245.598 us; speedup 1.0000x reference)
//
#include <hip/hip_runtime.h>

#define HW 4608      // 48*96
#define NB 16
#define CC 256
#define SS 64
#define EPS 1e-5f
#define NSPLIT 24    // k_graph split-K

typedef __attribute__((ext_vector_type(8))) short short8;
typedef __attribute__((ext_vector_type(4))) float f32x4;

__device__ __forceinline__ ushort f2bf(float f) {
    uint u = __float_as_uint(f);
    return (ushort)((u + 0x7FFFu + ((u >> 16) & 1u)) >> 16);
}
__device__ __forceinline__ float bf2f(ushort h) {
    return __uint_as_float(((uint)h) << 16);
}

// ---------------- K0: pack W fragment-ready: Wf[cs][kq][r][j] bf16, c = cs*32+kq*8+j ----------
__global__ __launch_bounds__(256) void k_wf(const float* __restrict__ Ws,
                                            const float* __restrict__ Wp,
                                            ushort* __restrict__ Wf) {
    int idx = blockIdx.x * 256 + threadIdx.x;      // 0..32767
    int j = idx & 7, r = (idx >> 3) & 127, kq = (idx >> 10) & 3, cs = idx >> 12;
    int c = cs * 32 + kq * 8 + j;
    float v = (r < 64) ? Ws[r * CC + c] : Wp[(r - 64) * CC + c];
    Wf[idx] = f2bf(v);
}

// ---------------- K1: MFMA proj, LDS-free, barrier-free, software-pipelined ----------------
// grid (72, NB), 256 thr. Block tile 128r x 64k; wave (wr,wn): 64r x 32k -> 4x2 MFMA tiles.
__global__ __launch_bounds__(256) void k_proj(const float* __restrict__ x,
                                              const ushort* __restrict__ Wf,
                                              const float* __restrict__ bs,
                                              const float* __restrict__ bp,
                                              const float* __restrict__ edge,
                                              ushort* __restrict__ xsb,
                                              ushort* __restrict__ Eb,
                                              float* __restrict__ rsum) {
    int n = blockIdx.y, k0 = blockIdx.x * 64;
    int tid = threadIdx.x, lane = tid & 63, w = tid >> 6;
    int wr = w >> 1, wn = w & 1;
    int q = lane >> 4, li = lane & 15;
    // B-operand base: col = k0 + wn*32 + nt*16 + li ; row = cs*32 + q*8 + j
    const float* xb = x + (size_t)n * CC * HW + k0 + wn * 32 + li;

    float pfB[2][2][8];      // [buf][nt][j] raw fp32
    short8 af[2][4];         // [buf][m]
    f32x4 acc[4][2] = {};

    // prologue: cs = 0 loads
#pragma unroll
    for (int nt = 0; nt < 2; nt++)
#pragma unroll
        for (int j = 0; j < 8; j++)
            pfB[0][nt][j] = xb[(size_t)(q * 8 + j) * HW + nt * 16];
#pragma unroll
    for (int m = 0; m < 4; m++) {
        int r = wr * 64 + m * 16 + li;
        uint4 t = *(const uint4*)&Wf[((0 * 4 + q) * 128 + r) * 8];
        af[0][m] = *(short8*)&t;
    }

#pragma unroll
    for (int cs = 0; cs < 8; cs++) {
        int cur = cs & 1, nxt = cur ^ 1;
        if (cs < 7) {   // issue next-step loads first (stay in flight through MFMAs)
#pragma unroll
            for (int nt = 0; nt < 2; nt++)
#pragma unroll
                for (int j = 0; j < 8; j++)
                    pfB[nxt][nt][j] = xb[(size_t)((cs + 1) * 32 + q * 8 + j) * HW + nt * 16];
#pragma unroll
            for (int m = 0; m < 4; m++) {
                int r = wr * 64 + m * 16 + li;
                uint4 t = *(const uint4*)&Wf[(((cs + 1) * 4 + q) * 128 + r) * 8];
                af[nxt][m] = *(short8*)&t;
            }
        }
        short8 bfr[2];
#pragma unroll
        for (int nt = 0; nt < 2; nt++) {
            union { ushort u[8]; short8 s; } tmp;
#pragma unroll
            for (int j = 0; j < 8; j++) tmp.u[j] = f2bf(pfB[cur][nt][j]);
            bfr[nt] = tmp.s;
        }
#pragma unroll
        for (int m = 0; m < 4; m++)
#pragma unroll
            for (int nt = 0; nt < 2; nt++)
                acc[m][nt] = __builtin_amdgcn_mfma_f32_16x16x32_bf16(af[cur][m], bfr[nt], acc[m][nt], 0, 0, 0);
    }

    // epilogue: rows wr*64 + m*16 + q*4 + rr ; cols k0 + wn*32 + nt*16 + li
    if (wr == 0) {
#pragma unroll
        for (int m = 0; m < 4; m++) {
#pragma unroll
            for (int rr = 0; rr < 4; rr++) {
                int s = m * 16 + q * 4 + rr;
                float bv = bs[s];
#pragma unroll
                for (int nt = 0; nt < 2; nt++) {
                    int col = k0 + wn * 32 + nt * 16 + li;
                    xsb[((size_t)n * SS + s) * HW + col] = f2bf(acc[m][nt][rr] + bv);
                }
            }
        }
    } else {
        float ga[2];
#pragma unroll
        for (int nt = 0; nt < 2; nt++) {
            int col = k0 + wn * 32 + nt * 16 + li;
            float e0 = edge[((size_t)n * 2 + 0) * HW + col];
            float e1 = edge[((size_t)n * 2 + 1) * HW + col];
            ga[nt] = 1.f + 1.f / (1.f + __expf(e0 - e1));
        }
        float rp[4][4];
#pragma unroll
        for (int m = 0; m < 4; m++) {
#pragma unroll
            for (int rr = 0; rr < 4; rr++) {
                int s = m * 16 + q * 4 + rr;
                float bv = bp[s];
                float sum = 0.f;
#pragma unroll
                for (int nt = 0; nt < 2; nt++) {
                    int col = k0 + wn * 32 + nt * 16 + li;
                    float e = __expf((acc[m][nt][rr] + bv) * ga[nt]);
                    sum += e;
                    Eb[((size_t)n * SS + s) * HW + col] = f2bf(e);
                }
                rp[m][rr] = sum;
            }
        }
#pragma unroll
        for (int b = 1; b < 16; b <<= 1)
#pragma unroll
            for (int m = 0; m < 4; m++)
#pragma unroll
                for (int rr = 0; rr < 4; rr++)
                    rp[m][rr] += __shfl_xor(rp[m][rr], b, 64);
        if (li == 0) {
#pragma unroll
            for (int m = 0; m < 4; m++)
#pragma unroll
                for (int rr = 0; rr < 4; rr++)
                    atomicAdd(&rsum[n * SS + m * 16 + q * 4 + rr], rp[m][rr]);
        }
    }
}

// ---------------- K2: MFMA graph: U = xs@E^T, P = E@E^T, split-K partials, pipelined ---------
// grid (NSPLIT, NB). Waves 0,1: U halves; waves 2,3: P halves. K/block = HW/NSPLIT = 192.
__global__ __launch_bounds__(256) void k_graph(const ushort* __restrict__ xsb,
                                               const ushort* __restrict__ Eb,
                                               float* __restrict__ Up,
                                               float* __restrict__ Pp) {
    int n = blockIdx.y, sp = blockIdx.x;
    int kbase = sp * (HW / NSPLIT);
    int tid = threadIdx.x, lane = tid & 63, w = tid >> 6;
    int q = lane >> 4, li = lane & 15;
    bool isP = w >= 2;
    int half = w & 1;
    const ushort* Arow = isP ? Eb : xsb;
    const int NITER = (HW / NSPLIT) / 32;   // 6
    f32x4 acc[2][4] = {};
    short8 af[2][2], bfr[2][4];
    {
        int kb = kbase + q * 8;
#pragma unroll
        for (int mt = 0; mt < 2; mt++) {
            int s = half * 32 + mt * 16 + li;
            uint4 t = *(const uint4*)&Arow[((size_t)n * SS + s) * HW + kb];
            af[0][mt] = *(short8*)&t;
        }
#pragma unroll
        for (int nt = 0; nt < 4; nt++) {
            int tt = nt * 16 + li;
            uint4 t = *(const uint4*)&Eb[((size_t)n * SS + tt) * HW + kb];
            bfr[0][nt] = *(short8*)&t;
        }
    }
#pragma unroll
    for (int ks = 0; ks < NITER; ks++) {
        int cur = ks & 1, nxt = cur ^ 1;
        if (ks < NITER - 1) {
            int kb = kbase + (ks + 1) * 32 + q * 8;
#pragma unroll
            for (int mt = 0; mt < 2; mt++) {
                int s = half * 32 + mt * 16 + li;
                uint4 t = *(const uint4*)&Arow[((size_t)n * SS + s) * HW + kb];
                af[nxt][mt] = *(short8*)&t;
            }
#pragma unroll
            for (int nt = 0; nt < 4; nt++) {
                int tt = nt * 16 + li;
                uint4 t = *(const uint4*)&Eb[((size_t)n * SS + tt) * HW + kb];
                bfr[nxt][nt] = *(short8*)&t;
            }
        }
#pragma unroll
        for (int mt = 0; mt < 2; mt++)
#pragma unroll
            for (int nt = 0; nt < 4; nt++)
                acc[mt][nt] = __builtin_amdgcn_mfma_f32_16x16x32_bf16(af[cur][mt], bfr[cur][nt], acc[mt][nt], 0, 0, 0);
    }
    float* dst = (isP ? Pp : Up) + ((size_t)sp * NB + n) * 4096;
#pragma unroll
    for (int mt = 0; mt < 2; mt++)
#pragma unroll
        for (int nt = 0; nt < 4; nt++)
#pragma unroll
            for (int rr = 0; rr < 4; rr++) {
                int row = half * 32 + mt * 16 + q * 4 + rr;
                int col = nt * 16 + li;
                dst[row * 64 + col] = acc[mt][nt][rr];
            }
}

// ---------------- K2b: reduce split-K partials ----------------
__global__ __launch_bounds__(256) void k_red(const float* __restrict__ Up,
                                             const float* __restrict__ Pp,
                                             float* __restrict__ U,
                                             float* __restrict__ P) {
    int idx = blockIdx.x * 256 + threadIdx.x;    // 0..131071
    const float* src = (idx < 65536) ? Up : Pp;
    float* dst = (idx < 65536) ? U : P;
    int o = idx & 65535;
    float s = 0.f;
    for (int sp = 0; sp < NSPLIT; sp++) s += src[(size_t)sp * 65536 + o];
    dst[o] = s;
}

// ---------------- K3: GCN + fold We: M' fp32 [c][t] AND bf16 fragment-ready Mf --------------
__global__ __launch_bounds__(256) void k_gcn(const float* __restrict__ U,
                                             const float* __restrict__ rsum,
                                             const float* __restrict__ W1,
                                             const float* __restrict__ W2,
                                             const float* __restrict__ We,
                                             float* __restrict__ M,
                                             ushort* __restrict__ Mf) {
    __shared__ __align__(16) float A[64 * 68];
    __shared__ __align__(16) float B[64 * 68];
    __shared__ __align__(16) float Cb[64 * 68];
    __shared__ float rs[64];
    int n = blockIdx.x;
    int cc = blockIdx.y;
    int tid = threadIdx.x;
    int t0 = tid >> 4, t1 = tid & 15;
    if (tid < 64) rs[tid] = 1.0f / rsum[n * SS + tid];
    __syncthreads();
#pragma unroll
    for (int i = 0; i < 16; i++) {
        int idx = tid + i * 256;
        int r = idx >> 6, cth = idx & 63;
        A[cth * 68 + r] = U[n * 4096 + idx] * rs[cth];
        B[cth * 68 + r] = W1[idx];
    }
    __syncthreads();
    {
        float acc[4][4] = {};
        for (int j = 0; j < 64; j++) {
            float4 a4 = *(const float4*)&A[j * 68 + t0 * 4];
            float4 b4 = *(const float4*)&B[j * 68 + t1 * 4];
            float a[4] = {a4.x, a4.y, a4.z, a4.w};
            float b[4] = {b4.x, b4.y, b4.z, b4.w};
#pragma unroll
            for (int p = 0; p < 4; p++)
#pragma unroll
                for (int qq = 0; qq < 4; qq++) acc[p][qq] += a[p] * b[qq];
        }
#pragma unroll
        for (int p = 0; p < 4; p++)
#pragma unroll
            for (int qq = 0; qq < 4; qq++) {
                acc[p][qq] -= A[(t1 * 4 + qq) * 68 + (t0 * 4 + p)];
                Cb[(t0 * 4 + p) * 68 + t1 * 4 + qq] = acc[p][qq];
            }
    }
    __syncthreads();
#pragma unroll
    for (int i = 0; i < 16; i++) {
        int idx = tid + i * 256;
        int r = idx >> 6, cth = idx & 63;
        B[cth * 68 + r] = W2[idx];
    }
    __syncthreads();
    {
        float acc[4][4] = {};
        for (int j = 0; j < 64; j++) {
            float4 a4 = *(const float4*)&B[j * 68 + t0 * 4];
            float4 b4 = *(const float4*)&Cb[j * 68 + t1 * 4];
            float a[4] = {a4.x, a4.y, a4.z, a4.w};
            float b[4] = {b4.x, b4.y, b4.z, b4.w};
#pragma unroll
            for (int p = 0; p < 4; p++)
#pragma unroll
                for (int qq = 0; qq < 4; qq++) acc[p][qq] += a[p] * b[qq];
        }
        __syncthreads();
#pragma unroll
        for (int p = 0; p < 4; p++)
#pragma unroll
            for (int qq = 0; qq < 4; qq++)
                A[(t0 * 4 + p) * 68 + t1 * 4 + qq] = fmaxf(acc[p][qq], 0.f);
    }
    __syncthreads();
#pragma unroll
    for (int i = 0; i < 16; i++) {
        int idx = tid + i * 256;
        int c = idx >> 6, j = idx & 63;
        B[j * 68 + c] = We[(cc * 64 + c) * 64 + j];
    }
    __syncthreads();
    {
        float acc[4][4] = {};
        for (int j = 0; j < 64; j++) {
            float4 a4 = *(const float4*)&B[j * 68 + t0 * 4];
            float4 b4 = *(const float4*)&A[j * 68 + t1 * 4];
            float a[4] = {a4.x, a4.y, a4.z, a4.w};
            float b[4] = {b4.x, b4.y, b4.z, b4.w};
#pragma unroll
            for (int p = 0; p < 4; p++)
#pragma unroll
                for (int qq = 0; qq < 4; qq++) acc[p][qq] += a[p] * b[qq];
        }
#pragma unroll
        for (int p = 0; p < 4; p++) {
            int c = cc * 64 + t0 * 4 + p;
            float v[4];
#pragma unroll
            for (int qq = 0; qq < 4; qq++) v[qq] = acc[p][qq] * rs[t1 * 4 + qq];
            float4 st = {v[0], v[1], v[2], v[3]};
            *(float4*)&M[((size_t)n * CC + c) * 64 + t1 * 4] = st;
#pragma unroll
            for (int qq = 0; qq < 4; qq++) {
                int t = t1 * 4 + qq;
                Mf[(size_t)n * 16384 + ((t >> 3) * 256 + c) * 8 + (t & 7)] = f2bf(v[qq]);
            }
        }
    }
}

// ---------------- K4: BN stats -> scale/bias ----------------
__global__ __launch_bounds__(256) void k_stats(const float* __restrict__ M,
                                               const float* __restrict__ P,
                                               const float* __restrict__ rsum,
                                               const float* __restrict__ gamma,
                                               const float* __restrict__ beta,
                                               float* __restrict__ sc,
                                               float* __restrict__ bi) {
    __shared__ float ms[64];
    __shared__ float rst[64];
    __shared__ float red[256];
    int c = blockIdx.x;
    int tid = threadIdx.x;
    float qa = 0.f, sa = 0.f;
    for (int n = 0; n < NB; n++) {
        if (tid < 64) ms[tid] = M[((size_t)n * CC + c) * 64 + tid];
        else if (tid < 128) rst[tid - 64] = rsum[n * SS + tid - 64];
        __syncthreads();
#pragma unroll
        for (int p = 0; p < 16; p++) {
            int e = p * 256 + tid;
            qa += ms[e >> 6] * ms[e & 63] * P[n * 4096 + e];
        }
        if ((tid & 63) == 0) {
#pragma unroll
            for (int p = 0; p < 16; p++) {
                int s = (p * 256 + tid) >> 6;
                sa += ms[s] * rst[s];
            }
        }
        __syncthreads();
    }
    red[tid] = qa;
    __syncthreads();
    for (int off = 128; off > 0; off >>= 1) {
        if (tid < off) red[tid] += red[tid + off];
        __syncthreads();
    }
    float qtot = red[0];
    __syncthreads();
    red[tid] = sa;
    __syncthreads();
    for (int off = 128; off > 0; off >>= 1) {
        if (tid < off) red[tid] += red[tid + off];
        __syncthreads();
    }
    float stot = red[0];
    if (tid == 0) {
        const float invM = 1.0f / ((float)NB * (float)HW);
        float mean = stot * invM;
        float var = qtot * invM - mean * mean;
        float s = gamma[c] * rsqrtf(var + EPS);
        sc[c] = s;
        bi[c] = beta[c] - s * mean;
    }
}

// ---------------- K5: MFMA out: out = x + sc[c]*(M' @ E)[c,k] + bi[c] ----------------
// grid (72, NB): block 256c x 64hw, K=64 (2 MFMA steps). A direct from Mf; B via LDS.
__global__ __launch_bounds__(256) void k_out(const float* __restrict__ x,
                                             const ushort* __restrict__ Mf,
                                             const ushort* __restrict__ Eb,
                                             const float* __restrict__ sc,
                                             const float* __restrict__ bi,
                                             float* __restrict__ out) {
    __shared__ __align__(16) ushort Bl[8 * 64 * 8];    // [kq][n][8] = 8 KB
    int n = blockIdx.y, k0 = blockIdx.x * 64;
    int tid = threadIdx.x, lane = tid & 63, w = tid >> 6;
    int q = lane >> 4, li = lane & 15;
    {
        int nl = tid & 63, pr = tid >> 6;
#pragma unroll
        for (int kk = 0; kk < 2; kk++) {
            int kq = pr * 2 + kk;
            union { ushort u[8]; uint4 v; } tmp;
#pragma unroll
            for (int j = 0; j < 8; j++)
                tmp.u[j] = Eb[((size_t)n * SS + kq * 8 + j) * HW + k0 + nl];
            *(uint4*)&Bl[(kq * 64 + nl) * 8] = tmp.v;
        }
    }
    __syncthreads();
    f32x4 acc[4][4] = {};
#pragma unroll
    for (int ks = 0; ks < 2; ks++) {
        short8 af[4], bfr[4];
#pragma unroll
        for (int mt = 0; mt < 4; mt++) {
            int c = w * 64 + mt * 16 + li;
            uint4 t = *(const uint4*)&Mf[(size_t)n * 16384 + ((ks * 4 + q) * 256 + c) * 8];
            af[mt] = *(short8*)&t;
        }
#pragma unroll
        for (int nt = 0; nt < 4; nt++) {
            int nl = nt * 16 + li;
            uint4 t = *(const uint4*)&Bl[((ks * 4 + q) * 64 + nl) * 8];
            bfr[nt] = *(short8*)&t;
        }
#pragma unroll
        for (int mt = 0; mt < 4; mt++)
#pragma unroll
            for (int nt = 0; nt < 4; nt++)
                acc[mt][nt] = __builtin_amdgcn_mfma_f32_16x16x32_bf16(af[mt], bfr[nt], acc[mt][nt], 0, 0, 0);
    }
#pragma unroll
    for (int mt = 0; mt < 4; mt++) {
        // hoist this mt-group's x loads so they're all in flight before the FMA+stores
        float xv[4][4];
#pragma unroll
        for (int rr = 0; rr < 4; rr++) {
            int c = w * 64 + mt * 16 + q * 4 + rr;
            size_t base = ((size_t)n * CC + c) * HW + k0;
#pragma unroll
            for (int nt = 0; nt < 4; nt++)
                xv[rr][nt] = x[base + nt * 16 + li];
        }
#pragma unroll
        for (int rr = 0; rr < 4; rr++) {
            int c = w * 64 + mt * 16 + q * 4 + rr;
            float s_ = sc[c], bv = bi[c];
            size_t base = ((size_t)n * CC + c) * HW + k0;
#pragma unroll
            for (int nt = 0; nt < 4; nt++) {
                int col = nt * 16 + li;
                out[base + col] = xv[rr][nt] + s_ * acc[mt][nt][rr] + bv;
            }
        }
    }
}

extern "C" void kernel_launch(void* const* d_in, const int* in_sizes, int n_in,
                              void* d_out, int out_size, void* d_ws, size_t ws_size,
                              hipStream_t stream) {
    const float* x = (const float*)d_in[0];
    const float* edge = (const float*)d_in[1];
    const float* Ws = (const float*)d_in[2];
    const float* bs = (const float*)d_in[3];
    const float* Wp = (const float*)d_in[4];
    const float* bp = (const float*)d_in[5];
    const float* W1 = (const float*)d_in[6];
    const float* W2 = (const float*)d_in[7];
    const float* We = (const float*)d_in[8];
    const float* gamma = (const float*)d_in[9];
    const float* beta = (const float*)d_in[10];
    float* out = (float*)d_out;

    char* base = (char*)d_ws;
    ushort* Wf  = (ushort*)base;                    base += 65536;           // 64 KB
    ushort* xsb = (ushort*)base;                    base += 9437184;         // 9 MB
    ushort* Eb  = (ushort*)base;                    base += 9437184;
    float*  Up  = (float*)base;                     base += (size_t)NSPLIT * NB * 4096 * 4;
    float*  Pp  = (float*)base;                     base += (size_t)NSPLIT * NB * 4096 * 4;
    float*  U   = (float*)base;                     base += 262144;
    float*  P   = (float*)base;                     base += 262144;
    float*  rsum= (float*)base;                     base += 4096;
    float*  M   = (float*)base;                     base += 1048576;
    ushort* Mf  = (ushort*)base;                    base += 524288;
    float*  sc  = (float*)base;                     base += 1024;
    float*  bi  = (float*)base;                     base += 1024;

    hipMemsetAsync(rsum, 0, 1024 * sizeof(float), stream);
    k_wf<<<128, 256, 0, stream>>>(Ws, Wp, Wf);
    k_proj<<<dim3(72, NB), 256, 0, stream>>>(x, Wf, bs, bp, edge, xsb, Eb, rsum);
    k_graph<<<dim3(NSPLIT, NB), 256, 0, stream>>>(xsb, Eb, Up, Pp);
    k_red<<<512, 256, 0, stream>>>(Up, Pp, U, P);
    k_gcn<<<dim3(NB, 4), 256, 0, stream>>>(U, rsum, W1, W2, We, M, Mf);
    k_stats<<<256, 256, 0, stream>>>(M, P, rsum, gamma, beta, sc, bi);
    k_out<<<dim3(72, NB), 256, 0, stream>>>(x, Mf, Eb, sc, bi, out);
}